// Round 1
// baseline (1845.474 us; speedup 1.0000x reference)
//
#include <hip/hip_runtime.h>

constexpr int cN     = 131072;   // nodes
constexpr int cE     = 2097152;  // edges
constexpr int cB     = 256;      // graphs
constexpr int cNPG   = 512;      // nodes/graph
constexpr int cEPG   = 8192;     // edges/graph
constexpr int cTOT   = 97;       // concat feature width
constexpr int cK     = 30;       // sort-pool k
constexpr int cS     = 5;
constexpr int cV     = 5000;
constexpr int cDENSE = 352;

// ---------------------------------------------------------------------------
// Kernel A: per-graph e2n scatter (LDS atomics), in-degree, packed edge list.
// ---------------------------------------------------------------------------
__global__ __launch_bounds__(512, 1)
void prep_kernel(const int* __restrict__ ei, const float* __restrict__ attr,
                 float* __restrict__ e2n, float* __restrict__ dis,
                 unsigned int* __restrict__ pk)
{
    __shared__ float acc[cNPG * 9];   // stride 9 breaks bank aliasing
    __shared__ int   ideg[cNPG];
    const int g = blockIdx.x, tid = threadIdx.x;
    for (int i = tid; i < cNPG * 9; i += 512) acc[i] = 0.f;
    if (tid < cNPG) ideg[tid] = 0;
    __syncthreads();
    const int ebase = g * cEPG;
    const int nbase = g * cNPG;
    for (int e = tid; e < cEPG; e += 512) {
        const int eg  = ebase + e;
        const int ls  = ei[eg]      - nbase;
        const int ld  = ei[cE + eg] - nbase;
        pk[eg] = (unsigned)ls | ((unsigned)ld << 16);
        const float4 a0 = *reinterpret_cast<const float4*>(attr + (size_t)eg * 8);
        const float4 a1 = *reinterpret_cast<const float4*>(attr + (size_t)eg * 8 + 4);
        atomicAdd(&acc[ls*9+0], a0.x); atomicAdd(&acc[ls*9+1], a0.y);
        atomicAdd(&acc[ls*9+2], a0.z); atomicAdd(&acc[ls*9+3], a0.w);
        atomicAdd(&acc[ls*9+4], a1.x); atomicAdd(&acc[ls*9+5], a1.y);
        atomicAdd(&acc[ls*9+6], a1.z); atomicAdd(&acc[ls*9+7], a1.w);
        if (ld != ls) {  // ref: dst add masked when dst==src
            atomicAdd(&acc[ld*9+0], a0.x); atomicAdd(&acc[ld*9+1], a0.y);
            atomicAdd(&acc[ld*9+2], a0.z); atomicAdd(&acc[ld*9+3], a0.w);
            atomicAdd(&acc[ld*9+4], a1.x); atomicAdd(&acc[ld*9+5], a1.y);
            atomicAdd(&acc[ld*9+6], a1.z); atomicAdd(&acc[ld*9+7], a1.w);
        }
        atomicAdd(&ideg[ld], 1);      // deg counts every dst occurrence
    }
    __syncthreads();
    for (int it = tid; it < cNPG * 8; it += 512) {
        const int l = it >> 3, c = it & 7;
        e2n[(size_t)g * cNPG * 8 + it] = acc[l * 9 + c];
    }
    if (tid < cNPG)
        dis[nbase + tid] = 1.0f / sqrtf((float)(1 + ideg[tid]));  // deg>=1 always
}

// ---------------------------------------------------------------------------
// Kernel B: TEDE[r][c]: rows 0..99 = node_emb@W0[0:256], 100..119 = depth_emb@W0[0:256]
// ---------------------------------------------------------------------------
__global__ __launch_bounds__(64, 1)
void embw0_kernel(const float* __restrict__ ne, const float* __restrict__ de,
                  const float* __restrict__ W0, float* __restrict__ TEDE)
{
    const int r = blockIdx.x * 2 + (threadIdx.x >> 5);
    const int c = threadIdx.x & 31;
    const float* src = (r < 100) ? (ne + (size_t)r * 256) : (de + (size_t)(r - 100) * 256);
    float s = 0.f;
    for (int k = 0; k < 256; ++k) s = fmaf(src[k], W0[k * 32 + c], s);
    TEDE[r * 32 + c] = s;
}

// ---------------------------------------------------------------------------
// Kernel C: one GCN layer, one block per graph.
//   u[n] = (t[n] @ W) * dis[n];  out[d] = b + dis[d]*(sum_{e->d} u[src] + u[d]); tanh
// ---------------------------------------------------------------------------
template<int LAYER>
__global__ __launch_bounds__(512, 1)
void gcn_layer_k(const float* __restrict__ hprev, const float* __restrict__ W,
                 const float* __restrict__ bias, const float* __restrict__ dis,
                 const unsigned int* __restrict__ pk,
                 float* __restrict__ hout, float* __restrict__ msg,
                 const int* __restrict__ ntype, const int* __restrict__ ndepth,
                 const float* __restrict__ e2n, const float* __restrict__ TEDE)
{
    constexpr int WID = (LAYER == 3) ? 1 : 32;
    constexpr int UN  = cNPG * WID;
    extern __shared__ float smem[];
    float* u   = smem;            // [cNPG * WID]
    float* acc = smem + UN;       // [cNPG * WID]
    float* Wl  = smem + 2 * UN;   // [<=1024]
    const int g = blockIdx.x, tid = threadIdx.x;
    const int nbase = g * cNPG;

    // stage weights into LDS
    if (LAYER == 0) {
        for (int i = tid; i < 8 * 32; i += 512) Wl[i] = W[256 * 32 + i]; // e2n rows of W0
    } else {
        for (int i = tid; i < 32 * WID; i += 512) Wl[i] = W[i];
    }

    // per-node register inputs (thread == local node)
    const int l = tid;
    const int n = nbase + l;
    const float dv = dis[n];
    float hr[32];
    int ty = 0, dp = 0;
    if (LAYER == 0) {
        ty = ntype[n]; dp = ndepth[n];
        const float4 a0 = *reinterpret_cast<const float4*>(e2n + (size_t)n * 8);
        const float4 a1 = *reinterpret_cast<const float4*>(e2n + (size_t)n * 8 + 4);
        hr[0]=a0.x; hr[1]=a0.y; hr[2]=a0.z; hr[3]=a0.w;
        hr[4]=a1.x; hr[5]=a1.y; hr[6]=a1.z; hr[7]=a1.w;
    } else {
        const float* hp = hprev + (size_t)n * 32;
        #pragma unroll
        for (int q = 0; q < 8; ++q) {
            const float4 x = *reinterpret_cast<const float4*>(hp + q * 4);
            hr[q*4+0]=x.x; hr[q*4+1]=x.y; hr[q*4+2]=x.z; hr[q*4+3]=x.w;
        }
    }
    __syncthreads();

    // u = (t @ W) * dis
    if (LAYER == 0) {
        #pragma unroll
        for (int c = 0; c < 32; ++c) {
            float s = TEDE[ty * 32 + c] + TEDE[(100 + dp) * 32 + c];
            #pragma unroll
            for (int f = 0; f < 8; ++f) s = fmaf(hr[f], Wl[f * 32 + c], s);
            u[l * 32 + c] = s * dv;
        }
    } else {
        #pragma unroll
        for (int c = 0; c < WID; ++c) {
            float s = 0.f;
            #pragma unroll
            for (int k = 0; k < 32; ++k) s = fmaf(hr[k], Wl[k * WID + c], s);
            u[l * WID + c] = s * dv;
        }
    }
    __syncthreads();
    for (int i = tid; i < UN; i += 512) acc[i] = 0.f;
    __syncthreads();

    // edge aggregation: acc[dst] += u[src]
    const unsigned int* pkg = pk + (size_t)g * cEPG;
    if (LAYER == 3) {
        for (int e = tid; e < cEPG; e += 512) {
            const unsigned int p = pkg[e];
            atomicAdd(&acc[p >> 16], u[p & 0xffffu]);
        }
    } else {
        for (int it = tid; it < cEPG * 32; it += 512) {
            const int e = it >> 5, c = it & 31;
            const unsigned int p = pkg[e];
            const int ls = (int)(p & 0xffffu);
            const int ld = (int)(p >> 16);
            atomicAdd(&acc[ld * 32 + c], u[ls * 32 + c]);
        }
    }
    __syncthreads();

    // epilogue: bias + self-loop + tanh
    if (LAYER == 3) {
        const float v = bias[0] + dv * (acc[l] + u[l]);
        msg[(size_t)n * cTOT + 96] = tanhf(v);
    } else {
        for (int it = tid; it < UN; it += 512) {
            const int ll = it >> 5, c = it & 31;
            const float v = bias[c] + dis[nbase + ll] * (acc[it] + u[it]);
            const float t = tanhf(v);
            hout[(size_t)nbase * 32 + it] = t;
            msg[(size_t)(nbase + ll) * cTOT + LAYER * 32 + c] = t;
        }
    }
}

// ---------------------------------------------------------------------------
// Kernel D: sort-pool ranks. Stable order: (key desc, index asc) == argsort(-key)
// ---------------------------------------------------------------------------
__global__ __launch_bounds__(512, 1)
void sortpool_kernel(const float* __restrict__ msg, int* __restrict__ order)
{
    __shared__ float key[cNPG];
    const int g = blockIdx.x, l = threadIdx.x;
    const float ki = msg[(size_t)(g * cNPG + l) * cTOT + 96];
    key[l] = ki;
    __syncthreads();
    int rank = 0;
    for (int j = 0; j < cNPG; ++j) {
        const float kj = key[j];
        rank += (kj > ki) || (kj == ki && j < l);
    }
    if (rank < cK) order[g * cK + rank] = g * cNPG + l;
}

// ---------------------------------------------------------------------------
// Kernel E: gather pooled + conv1 + relu + maxpool + conv2 + relu -> dense[B,352]
// ---------------------------------------------------------------------------
__global__ __launch_bounds__(512, 1)
void head_kernel(const float* __restrict__ msg, const int* __restrict__ order,
                 const float* __restrict__ c1w, const float* __restrict__ c1b,
                 const float* __restrict__ c2w, const float* __restrict__ c2b,
                 float* __restrict__ dense)
{
    __shared__ float P[cK * cTOT];      // 2910
    __shared__ float w1[16 * cTOT];     // 1552
    __shared__ float w2[32 * 16 * 5];   // 2560
    __shared__ float bb[48];
    __shared__ float Cb[16 * 30];
    __shared__ float Mb[16 * 15];
    const int g = blockIdx.x, tid = threadIdx.x;
    for (int i = tid; i < cK * cTOT; i += 512) {
        const int r = i / cTOT, ii = i - r * cTOT;
        P[i] = msg[(size_t)order[g * cK + r] * cTOT + ii];
    }
    for (int i = tid; i < 16 * cTOT; i += 512) w1[i] = c1w[i];
    for (int i = tid; i < 2560; i += 512) w2[i] = c2w[i];
    if (tid < 16) bb[tid] = c1b[tid];
    else if (tid < 48) bb[tid] = c2b[tid - 16];
    __syncthreads();
    if (tid < 480) {                           // conv1 (stride 97 == per-row dot)
        const int o = tid / 30, k = tid - o * 30;
        float s = bb[o];
        for (int i = 0; i < cTOT; ++i) s = fmaf(P[k * cTOT + i], w1[o * cTOT + i], s);
        Cb[tid] = fmaxf(s, 0.f);
    }
    __syncthreads();
    if (tid < 240) {                           // maxpool w=2 s=2
        const int o = tid / 15, p = tid - o * 15;
        Mb[tid] = fmaxf(Cb[o * 30 + 2 * p], Cb[o * 30 + 2 * p + 1]);
    }
    __syncthreads();
    if (tid < cDENSE) {                        // conv2 (kw=5) + relu
        const int o2 = tid / 11, q = tid - o2 * 11;
        float s = bb[16 + o2];
        #pragma unroll
        for (int i = 0; i < 16; ++i)
            #pragma unroll
            for (int w = 0; w < 5; ++w)
                s = fmaf(Mb[i * 15 + q + w], w2[(o2 * 16 + i) * 5 + w], s);
        dense[(size_t)g * cDENSE + tid] = fmaxf(s, 0.f);
    }
}

// ---------------------------------------------------------------------------
// Kernel F: preds[s,b,v] = dense[b,:] @ pred_w[s,:,v] + pred_b[s,v]
// 64 b-rows per block accumulated per-thread; dense read via uniform addresses.
// ---------------------------------------------------------------------------
__global__ __launch_bounds__(256, 1)
void pred_gemm_k(const float* __restrict__ dense, const float* __restrict__ pw,
                 const float* __restrict__ pb, float* __restrict__ out)
{
    const int v  = blockIdx.x * 256 + threadIdx.x;
    const int b0 = blockIdx.y * 64;
    const int s  = blockIdx.z;
    float acc[64];
    #pragma unroll
    for (int i = 0; i < 64; ++i) acc[i] = 0.f;
    if (v < cV) {
        const float* w  = pw + (size_t)s * cDENSE * cV + v;
        const float* dn = dense + (size_t)b0 * cDENSE;
        for (int d = 0; d < cDENSE; d += 4) {
            const float w0 = w[(size_t)(d + 0) * cV];
            const float w1 = w[(size_t)(d + 1) * cV];
            const float w2 = w[(size_t)(d + 2) * cV];
            const float w3 = w[(size_t)(d + 3) * cV];
            #pragma unroll
            for (int bi = 0; bi < 64; ++bi) {
                const float4 x = *reinterpret_cast<const float4*>(dn + bi * cDENSE + d);
                acc[bi] = fmaf(x.x, w0, fmaf(x.y, w1, fmaf(x.z, w2, fmaf(x.w, w3, acc[bi]))));
            }
        }
        const float pbv = pb[(size_t)s * cV + v];
        #pragma unroll
        for (int bi = 0; bi < 64; ++bi)
            out[((size_t)s * cB + (b0 + bi)) * cV + v] = acc[bi] + pbv;
    }
}

// ---------------------------------------------------------------------------
extern "C" void kernel_launch(void* const* d_in, const int* in_sizes, int n_in,
                              void* d_out, int out_size, void* d_ws, size_t ws_size,
                              hipStream_t stream)
{
    const int*   node_type  = (const int*)  d_in[0];
    const int*   node_depth = (const int*)  d_in[1];
    const int*   edge_index = (const int*)  d_in[2];
    const float* edge_attr  = (const float*)d_in[3];
    const float* node_emb   = (const float*)d_in[5];
    const float* depth_emb  = (const float*)d_in[6];
    const float* W0 = (const float*)d_in[7];  const float* b0 = (const float*)d_in[8];
    const float* W1 = (const float*)d_in[9];  const float* b1 = (const float*)d_in[10];
    const float* W2 = (const float*)d_in[11]; const float* b2 = (const float*)d_in[12];
    const float* W3 = (const float*)d_in[13]; const float* b3 = (const float*)d_in[14];
    const float* c1w = (const float*)d_in[15]; const float* c1b = (const float*)d_in[16];
    const float* c2w = (const float*)d_in[17]; const float* c2b = (const float*)d_in[18];
    const float* pw  = (const float*)d_in[19]; const float* pb  = (const float*)d_in[20];
    float* out = (float*)d_out;

    char* p = (char*)d_ws;
    auto carve = [&](size_t bytes) { void* r = (void*)p; p += (bytes + 255) & ~(size_t)255; return r; };
    float*        e2n   = (float*)       carve((size_t)cN * 8 * 4);        // 4 MB
    float*        dis   = (float*)       carve((size_t)cN * 4);            // 0.5 MB
    unsigned int* pk    = (unsigned int*)carve((size_t)cE * 4);            // 8 MB
    float*        h     = (float*)       carve((size_t)cN * 32 * 4);       // 16 MB
    float*        msg   = (float*)       carve((size_t)cN * cTOT * 4);     // 50.9 MB
    int*          order = (int*)         carve((size_t)cB * cK * 4);
    float*        dense = (float*)       carve((size_t)cB * cDENSE * 4);
    float*        TEDE  = (float*)       carve((size_t)120 * 32 * 4);

    const int GCN_LDS = (2 * cNPG * 32 + 1024) * 4;   // 135168 B
    hipFuncSetAttribute(reinterpret_cast<const void*>(&gcn_layer_k<0>),
                        hipFuncAttributeMaxDynamicSharedMemorySize, GCN_LDS);
    hipFuncSetAttribute(reinterpret_cast<const void*>(&gcn_layer_k<1>),
                        hipFuncAttributeMaxDynamicSharedMemorySize, GCN_LDS);
    hipFuncSetAttribute(reinterpret_cast<const void*>(&gcn_layer_k<2>),
                        hipFuncAttributeMaxDynamicSharedMemorySize, GCN_LDS);

    prep_kernel<<<cB, 512, 0, stream>>>(edge_index, edge_attr, e2n, dis, pk);
    embw0_kernel<<<60, 64, 0, stream>>>(node_emb, depth_emb, W0, TEDE);
    gcn_layer_k<0><<<cB, 512, GCN_LDS, stream>>>(nullptr, W0, b0, dis, pk, h, msg,
                                                 node_type, node_depth, e2n, TEDE);
    gcn_layer_k<1><<<cB, 512, GCN_LDS, stream>>>(h, W1, b1, dis, pk, h, msg,
                                                 nullptr, nullptr, nullptr, nullptr);
    gcn_layer_k<2><<<cB, 512, GCN_LDS, stream>>>(h, W2, b2, dis, pk, h, msg,
                                                 nullptr, nullptr, nullptr, nullptr);
    gcn_layer_k<3><<<cB, 512, (2 * cNPG + 1024) * 4, stream>>>(h, W3, b3, dis, pk, nullptr, msg,
                                                 nullptr, nullptr, nullptr, nullptr);
    sortpool_kernel<<<cB, 512, 0, stream>>>(msg, order);
    head_kernel<<<cB, 512, 0, stream>>>(msg, order, c1w, c1b, c2w, c2b, dense);
    pred_gemm_k<<<dim3(20, 4, 5), 256, 0, stream>>>(dense, pw, pb, out);
    (void)in_sizes; (void)n_in; (void)out_size; (void)ws_size;
}

// Round 4
// 558.181 us; speedup vs baseline: 3.3062x; 3.3062x over previous
//
#include <hip/hip_runtime.h>

typedef unsigned short ushort_t;

constexpr int cN     = 131072;
constexpr int cE     = 2097152;
constexpr int cB     = 256;
constexpr int cNPG   = 512;
constexpr int cEPG   = 8192;
constexpr int cTOT   = 97;
constexpr int cK     = 30;
constexpr int cV     = 5000;
constexpr int cDENSE = 352;

#define FMA4(A, S, W) \
    (A).x = fmaf((S), (W).x, (A).x); (A).y = fmaf((S), (W).y, (A).y); \
    (A).z = fmaf((S), (W).z, (A).z); (A).w = fmaf((S), (W).w, (A).w)

// acc += x * norm with SEPARATE mul/add roundings (match np scatter-add,
// prevent ffp-contract=fast fusing into fma)
#define MULADD4(A, X, NRM) \
    (A).x = __fadd_rn((A).x, __fmul_rn((X).x, (NRM))); \
    (A).y = __fadd_rn((A).y, __fmul_rn((X).y, (NRM))); \
    (A).z = __fadd_rn((A).z, __fmul_rn((X).z, (NRM))); \
    (A).w = __fadd_rn((A).w, __fmul_rn((X).w, (NRM)))

// ---------------------------------------------------------------------------
// prep: per-graph counting-sort into in-CSR + out-CSR, canonical (eid-sorted,
// deterministic) bucket order; e2n as two ascending-eid accumulators (ref:
// segsum(src) + segsum(masked dst)); dis; in-CSR exported for GCN layers.
// ---------------------------------------------------------------------------
__global__ __launch_bounds__(512, 1)
void prep_kernel(const int* __restrict__ ei, const float* __restrict__ attr,
                 float* __restrict__ e2n, float* __restrict__ dis,
                 ushort_t* __restrict__ in_src_g, int* __restrict__ in_off_g)
{
    __shared__ unsigned s_in[cEPG];     // (eid<<16)|src, sorted by eid per bucket
    __shared__ ushort_t s_out[cEPG];    // eid, sorted per bucket
    __shared__ int cnt[cNPG];           // packed: in<<16 | out
    __shared__ int woff[cNPG];
    const int g = blockIdx.x, tid = threadIdx.x;
    const int ebase = g * cEPG, nbase = g * cNPG;

    cnt[tid] = 0;
    __syncthreads();

    int er[16];
    #pragma unroll
    for (int j = 0; j < 16; ++j) {
        const int e  = tid + 512 * j;
        const int ls = ei[ebase + e]      - nbase;
        const int ld = ei[cE + ebase + e] - nbase;
        er[j] = ls | (ld << 16);
        atomicAdd(&cnt[ld], 65536);
        atomicAdd(&cnt[ls], 1);
    }
    __syncthreads();

    const int mycnt = cnt[tid];
    int run = mycnt;                       // inclusive scan (packed, in place)
    for (int d = 1; d < 512; d <<= 1) {
        const int add = (tid >= d) ? cnt[tid - d] : 0;
        __syncthreads();
        run += add;
        cnt[tid] = run;
        __syncthreads();
    }
    const int myexcl = run - mycnt;
    woff[tid] = myexcl;
    __syncthreads();

    #pragma unroll
    for (int j = 0; j < 16; ++j) {
        const int e  = tid + 512 * j;
        const int ls = er[j] & 0xffff;
        const int ld = er[j] >> 16;
        const int o1 = atomicAdd(&woff[ld], 65536);
        s_in[o1 >> 16] = ((unsigned)e << 16) | (unsigned)ls;
        const int o2 = atomicAdd(&woff[ls], 1);
        s_out[o2 & 0xffff] = (ushort_t)e;
    }
    __syncthreads();

    const int beg_in  = myexcl >> 16,     deg_in  = mycnt >> 16;
    const int beg_out = myexcl & 0xffff,  deg_out = mycnt & 0xffff;

    // canonical order: insertion-sort my buckets by eid (determinism)
    for (int j = beg_in + 1; j < beg_in + deg_in; ++j) {
        const unsigned x = s_in[j];
        int k = j - 1;
        while (k >= beg_in && s_in[k] > x) { s_in[k + 1] = s_in[k]; --k; }
        s_in[k + 1] = x;
    }
    for (int j = beg_out + 1; j < beg_out + deg_out; ++j) {
        const ushort_t x = s_out[j];
        int k = j - 1;
        while (k >= beg_out && s_out[k] > x) { s_out[k + 1] = s_out[k]; --k; }
        s_out[k + 1] = x;
    }
    __syncthreads();   // all buckets sorted before CSR export reads them

    // e2n: S1 = sum attr over out-edges (eid asc); S2 = sum over in-edges with
    // src != self (eid asc); e2n = S1 + S2   (matches ref's two segment_sums)
    float s1[8] = {0,0,0,0,0,0,0,0}, s2[8] = {0,0,0,0,0,0,0,0};
    for (int j = 0; j < deg_out; ++j) {
        const int eid = s_out[beg_out + j];
        const float4* ap = (const float4*)(attr + (size_t)(ebase + eid) * 8);
        const float4 x0 = ap[0], x1 = ap[1];
        s1[0] = __fadd_rn(s1[0], x0.x); s1[1] = __fadd_rn(s1[1], x0.y);
        s1[2] = __fadd_rn(s1[2], x0.z); s1[3] = __fadd_rn(s1[3], x0.w);
        s1[4] = __fadd_rn(s1[4], x1.x); s1[5] = __fadd_rn(s1[5], x1.y);
        s1[6] = __fadd_rn(s1[6], x1.z); s1[7] = __fadd_rn(s1[7], x1.w);
    }
    for (int j = 0; j < deg_in; ++j) {
        const unsigned v = s_in[beg_in + j];
        if ((int)(v & 0xffffu) != tid) {
            const int eid = (int)(v >> 16);
            const float4* ap = (const float4*)(attr + (size_t)(ebase + eid) * 8);
            const float4 x0 = ap[0], x1 = ap[1];
            s2[0] = __fadd_rn(s2[0], x0.x); s2[1] = __fadd_rn(s2[1], x0.y);
            s2[2] = __fadd_rn(s2[2], x0.z); s2[3] = __fadd_rn(s2[3], x0.w);
            s2[4] = __fadd_rn(s2[4], x1.x); s2[5] = __fadd_rn(s2[5], x1.y);
            s2[6] = __fadd_rn(s2[6], x1.z); s2[7] = __fadd_rn(s2[7], x1.w);
        }
    }
    float* eo = e2n + (size_t)(nbase + tid) * 8;
    #pragma unroll
    for (int c = 0; c < 8; ++c) eo[c] = __fadd_rn(s1[c], s2[c]);
    dis[nbase + tid] = 1.0f / sqrtf(1.0f + (float)deg_in);

    // export in-CSR (eid-sorted src lists), packed 2 per uint
    {
        unsigned* dst = (unsigned*)(in_src_g + (size_t)g * cEPG);
        for (int i = tid; i < cEPG / 2; i += 512)
            dst[i] = (s_in[2 * i] & 0xffffu) | ((s_in[2 * i + 1] & 0xffffu) << 16);
        in_off_g[g * 513 + tid] = beg_in;
        if (tid == 511) in_off_g[g * 513 + 512] = cEPG;
    }
}

// ---------------------------------------------------------------------------
// T2[(ty*20+dp)*32+c] = sum_k (ne[ty][k]+de[dp][k]) * W0[k][c], k ascending —
// exactly ref's x = ne[ty]+de[dp] (rounded add) then sequential-k fma dot.
// ---------------------------------------------------------------------------
__global__ __launch_bounds__(64, 1)
void tede2_kernel(const float* __restrict__ ne, const float* __restrict__ de,
                  const float* __restrict__ W0, float* __restrict__ T2)
{
    const int combo = blockIdx.x * 2 + (threadIdx.x >> 5);   // 0..1999
    const int c = threadIdx.x & 31;
    const int ty = combo / 20, dp = combo - ty * 20;
    const float* np_ = ne + (size_t)ty * 256;
    const float* dd_ = de + (size_t)dp * 256;
    float a = 0.f;
    for (int k = 0; k < 256; ++k)
        a = fmaf(__fadd_rn(np_[k], dd_[k]), W0[k * 32 + c], a);
    T2[(size_t)combo * 32 + c] = a;
}

// ---------------------------------------------------------------------------
// GCN layer, ref-order arithmetic:
//   hw[n] = h[n] @ W           (sequential-k fma, matches BLAS microkernel)
//   out[d] = sum_{in-edges, eid asc} hw[s]*(dis[s]*dis[d])   (mul+add, no fma)
//          + hw[d]*(dis[d]*dis[d])                           (self-loop LAST)
//          + bias; tanh (correctly rounded via double)
// LAYER 3 also does the sort-pool ranking.
// ---------------------------------------------------------------------------
template<int LAYER>
__global__ __launch_bounds__(512, 1)
void gcn_layer_k(const float* __restrict__ hprev, const float* __restrict__ Wg,
                 const float* __restrict__ bias, const float* __restrict__ dis,
                 const ushort_t* __restrict__ in_src, const int* __restrict__ in_off,
                 float* __restrict__ hout, float* __restrict__ msg,
                 const int* __restrict__ ntype, const int* __restrict__ ndepth,
                 const float* __restrict__ e2n, const float* __restrict__ T2,
                 int* __restrict__ order)
{
    constexpr bool THIN = (LAYER == 3);
    constexpr int USTR = THIN ? 1 : 36;            // bank-spreading stride
    extern __shared__ float smem[];
    float* u    = smem;                            // [512*USTR]
    float* disl = smem + 512 * USTR;               // [512]
    int* offl   = (int*)(disl + 512);              // [513->516]
    ushort_t* srcl = (ushort_t*)(offl + 516);      // [8192]
    float* key  = (float*)(srcl + cEPG);           // layer3 only [512]
    const int g = blockIdx.x, tid = threadIdx.x;
    const int n = g * cNPG + tid;

    {   // stage CSR + dis
        const uint4* s4 = (const uint4*)(in_src + (size_t)g * cEPG);
        uint4* d4 = (uint4*)srcl;
        for (int i = tid; i < cEPG / 8; i += 512) d4[i] = s4[i];
        offl[tid] = in_off[g * 513 + tid];
        if (tid == 0) offl[512] = cEPG;
    }
    const float dvd = dis[n];
    disl[tid] = dvd;

    if (!THIN) {
        float hw[32];
        if (LAYER == 0) {
            const int ty = ntype[n], dp = ndepth[n];
            float er[8];
            {
                const float4* ep = (const float4*)(e2n + (size_t)n * 8);
                const float4 x0 = ep[0], x1 = ep[1];
                er[0]=x0.x; er[1]=x0.y; er[2]=x0.z; er[3]=x0.w;
                er[4]=x1.x; er[5]=x1.y; er[6]=x1.z; er[7]=x1.w;
            }
            const float4* tp = (const float4*)(T2 + (size_t)(ty * 20 + dp) * 32);
            #pragma unroll
            for (int cq = 0; cq < 8; ++cq) {
                float4 a = tp[cq];              // k=0..255 already accumulated
                #pragma unroll
                for (int f = 0; f < 8; ++f) {   // continue chain k=256..263
                    const float4 wv = *(const float4*)(Wg + (256 + f) * 32 + cq * 4);
                    FMA4(a, er[f], wv);
                }
                hw[cq*4+0]=a.x; hw[cq*4+1]=a.y; hw[cq*4+2]=a.z; hw[cq*4+3]=a.w;
            }
        } else {
            float hr[32];
            const float4* hp = (const float4*)(hprev + (size_t)n * 32);
            #pragma unroll
            for (int q = 0; q < 8; ++q) {
                const float4 x = hp[q];
                hr[q*4+0]=x.x; hr[q*4+1]=x.y; hr[q*4+2]=x.z; hr[q*4+3]=x.w;
            }
            #pragma unroll
            for (int cq = 0; cq < 8; ++cq) {
                float4 a = {0.f, 0.f, 0.f, 0.f};
                #pragma unroll
                for (int k = 0; k < 32; ++k) {  // uniform address -> s_load
                    const float4 wv = *(const float4*)(Wg + k * 32 + cq * 4);
                    FMA4(a, hr[k], wv);
                }
                hw[cq*4+0]=a.x; hw[cq*4+1]=a.y; hw[cq*4+2]=a.z; hw[cq*4+3]=a.w;
            }
        }
        {
            float4* up = (float4*)(u + tid * 36);
            #pragma unroll
            for (int cq = 0; cq < 8; ++cq) {
                float4 o; o.x=hw[cq*4+0]; o.y=hw[cq*4+1];
                o.z=hw[cq*4+2]; o.w=hw[cq*4+3];
                up[cq] = o;
            }
        }
        __syncthreads();

        // edge gather (eid ascending), per-term (dis[s]*dis[d]) mul then add
        float4 acc[8];
        #pragma unroll
        for (int cq = 0; cq < 8; ++cq) acc[cq] = {0.f, 0.f, 0.f, 0.f};
        const int beg = offl[tid], dnum = offl[tid + 1] - beg;
        for (int j = 0; j < dnum; ++j) {
            const int s = srcl[beg + j];
            const float norm = __fmul_rn(disl[s], dvd);
            const float4* up = (const float4*)(u + s * 36);
            #pragma unroll
            for (int cq = 0; cq < 8; ++cq) {
                const float4 x = up[cq];
                MULADD4(acc[cq], x, norm);
            }
        }
        // self-loop LAST (ref: appended after all edges)
        {
            const float normS = __fmul_rn(dvd, dvd);
            const float4* up = (const float4*)(u + tid * 36);
            #pragma unroll
            for (int cq = 0; cq < 8; ++cq) {
                const float4 x = up[cq];
                MULADD4(acc[cq], x, normS);
            }
        }

        // + bias, tanh (correctly rounded)
        float outv[32];
        #pragma unroll
        for (int cq = 0; cq < 8; ++cq) {
            const float4 bv = *(const float4*)(bias + cq * 4);  // s_load
            outv[cq*4+0] = (float)tanh((double)__fadd_rn(acc[cq].x, bv.x));
            outv[cq*4+1] = (float)tanh((double)__fadd_rn(acc[cq].y, bv.y));
            outv[cq*4+2] = (float)tanh((double)__fadd_rn(acc[cq].z, bv.z));
            outv[cq*4+3] = (float)tanh((double)__fadd_rn(acc[cq].w, bv.w));
        }
        float4* ho = (float4*)(hout + (size_t)n * 32);
        #pragma unroll
        for (int cq = 0; cq < 8; ++cq) {
            float4 o; o.x = outv[cq*4+0]; o.y = outv[cq*4+1];
            o.z = outv[cq*4+2]; o.w = outv[cq*4+3];
            ho[cq] = o;
        }
        float* mrow = msg + (size_t)n * cTOT + LAYER * 32;
        #pragma unroll
        for (int c = 0; c < 32; ++c) mrow[c] = outv[c];
    } else {
        float hr[32];
        const float4* hp = (const float4*)(hprev + (size_t)n * 32);
        #pragma unroll
        for (int q = 0; q < 8; ++q) {
            const float4 x = hp[q];
            hr[q*4+0]=x.x; hr[q*4+1]=x.y; hr[q*4+2]=x.z; hr[q*4+3]=x.w;
        }
        float s_ = 0.f;
        #pragma unroll
        for (int k = 0; k < 32; ++k) s_ = fmaf(hr[k], Wg[k], s_);  // s_load
        u[tid] = s_;
        __syncthreads();
        const int beg = offl[tid], dnum = offl[tid + 1] - beg;
        float gs = 0.f;
        for (int j = 0; j < dnum; ++j) {
            const int s = srcl[beg + j];
            gs = __fadd_rn(gs, __fmul_rn(u[s], __fmul_rn(disl[s], dvd)));
        }
        gs = __fadd_rn(gs, __fmul_rn(u[tid], __fmul_rn(dvd, dvd)));  // self last
        const float o = (float)tanh((double)__fadd_rn(gs, bias[0]));
        msg[(size_t)n * cTOT + 96] = o;
        key[tid] = o;
        __syncthreads();
        // sort-pool rank (stable: desc key, asc index)
        int rank = 0;
        for (int jj = 0; jj < 128; ++jj) {
            const float4 kq = *(const float4*)(key + jj * 4);
            rank += (kq.x > o) || (kq.x == o && (jj*4+0) < tid);
            rank += (kq.y > o) || (kq.y == o && (jj*4+1) < tid);
            rank += (kq.z > o) || (kq.z == o && (jj*4+2) < tid);
            rank += (kq.w > o) || (kq.w == o && (jj*4+3) < tid);
        }
        if (rank < cK) order[g * cK + rank] = n;
    }
}

// ---------------------------------------------------------------------------
// head: gather pooled rows + conv1 + relu + maxpool + conv2 + relu -> dense
// ---------------------------------------------------------------------------
__global__ __launch_bounds__(512, 1)
void head_kernel(const float* __restrict__ msg, const int* __restrict__ order,
                 const float* __restrict__ c1w, const float* __restrict__ c1b,
                 const float* __restrict__ c2w, const float* __restrict__ c2b,
                 float* __restrict__ dense)
{
    __shared__ float P[cK * cTOT];
    __shared__ float w1[16 * cTOT];
    __shared__ float w2[32 * 16 * 5];
    __shared__ float bb[48];
    __shared__ float Cb[16 * 30];
    __shared__ float Mb[16 * 15];
    const int g = blockIdx.x, tid = threadIdx.x;
    for (int i = tid; i < cK * cTOT; i += 512) {
        const int r = i / cTOT, ii = i - r * cTOT;
        P[i] = msg[(size_t)order[g * cK + r] * cTOT + ii];
    }
    for (int i = tid; i < 16 * cTOT; i += 512) w1[i] = c1w[i];
    for (int i = tid; i < 2560; i += 512) w2[i] = c2w[i];
    if (tid < 16) bb[tid] = c1b[tid];
    else if (tid < 48) bb[tid] = c2b[tid - 16];
    __syncthreads();
    if (tid < 480) {
        const int o = tid / 30, k = tid - o * 30;
        float s = bb[o];
        for (int i = 0; i < cTOT; ++i) s = fmaf(P[k * cTOT + i], w1[o * cTOT + i], s);
        Cb[tid] = fmaxf(s, 0.f);
    }
    __syncthreads();
    if (tid < 240) {
        const int o = tid / 15, p = tid - o * 15;
        Mb[tid] = fmaxf(Cb[o * 30 + 2 * p], Cb[o * 30 + 2 * p + 1]);
    }
    __syncthreads();
    if (tid < cDENSE) {
        const int o2 = tid / 11, q = tid - o2 * 11;
        float s = bb[16 + o2];
        #pragma unroll
        for (int i = 0; i < 16; ++i)
            #pragma unroll
            for (int w = 0; w < 5; ++w)
                s = fmaf(Mb[i * 15 + q + w], w2[(o2 * 16 + i) * 5 + w], s);
        dense[(size_t)g * cDENSE + tid] = fmaxf(s, 0.f);
    }
}

// ---------------------------------------------------------------------------
// pred GEMM: [5x256, 352] @ [5][352, 5000]; dense via wave-uniform s_loads,
// pred_w streamed coalesced; thread tile 16b x 4v.
// ---------------------------------------------------------------------------
__global__ __launch_bounds__(256, 1)
void pred_gemm_k(const float* __restrict__ dense, const float* __restrict__ pw,
                 const float* __restrict__ pb, float* __restrict__ out)
{
    int w = threadIdx.x >> 6;
    w = __builtin_amdgcn_readfirstlane(w);         // wave-uniform -> SGPR
    const int lane = threadIdx.x & 63;
    const int s = blockIdx.z, b0 = blockIdx.y * 64;
    const int v = blockIdx.x * 256 + lane * 4;
    if (v >= cV) return;                            // 5000 % 4 == 0

    const float* dB = dense + (size_t)(b0 + w * 16) * cDENSE;  // uniform base
    const float* wp = pw + (size_t)s * cDENSE * cV + v;

    float4 acc[16];
    #pragma unroll
    for (int bi = 0; bi < 16; ++bi) acc[bi] = {0.f, 0.f, 0.f, 0.f};

    for (int k = 0; k < cDENSE; k += 4) {
        const float* wk = wp + (size_t)k * cV;
        const float4 w0 = *(const float4*)(wk);
        const float4 w1 = *(const float4*)(wk + cV);
        const float4 w2 = *(const float4*)(wk + 2 * cV);
        const float4 w3 = *(const float4*)(wk + 3 * cV);
        #pragma unroll
        for (int bi = 0; bi < 16; ++bi) {
            const float4 dq = *(const float4*)(dB + bi * cDENSE + k); // s_load x4
            FMA4(acc[bi], dq.x, w0);
            FMA4(acc[bi], dq.y, w1);
            FMA4(acc[bi], dq.z, w2);
            FMA4(acc[bi], dq.w, w3);
        }
    }
    const float4 pbv = *(const float4*)(pb + (size_t)s * cV + v);
    #pragma unroll
    for (int bi = 0; bi < 16; ++bi) {
        float4 o;
        o.x = acc[bi].x + pbv.x; o.y = acc[bi].y + pbv.y;
        o.z = acc[bi].z + pbv.z; o.w = acc[bi].w + pbv.w;
        *(float4*)(out + ((size_t)s * cB + b0 + w * 16 + bi) * cV + v) = o;
    }
}

// ---------------------------------------------------------------------------
extern "C" void kernel_launch(void* const* d_in, const int* in_sizes, int n_in,
                              void* d_out, int out_size, void* d_ws, size_t ws_size,
                              hipStream_t stream)
{
    const int*   node_type  = (const int*)  d_in[0];
    const int*   node_depth = (const int*)  d_in[1];
    const int*   edge_index = (const int*)  d_in[2];
    const float* edge_attr  = (const float*)d_in[3];
    const float* node_emb   = (const float*)d_in[5];
    const float* depth_emb  = (const float*)d_in[6];
    const float* W0 = (const float*)d_in[7];  const float* b0 = (const float*)d_in[8];
    const float* W1 = (const float*)d_in[9];  const float* b1 = (const float*)d_in[10];
    const float* W2 = (const float*)d_in[11]; const float* b2 = (const float*)d_in[12];
    const float* W3 = (const float*)d_in[13]; const float* b3 = (const float*)d_in[14];
    const float* c1w = (const float*)d_in[15]; const float* c1b = (const float*)d_in[16];
    const float* c2w = (const float*)d_in[17]; const float* c2b = (const float*)d_in[18];
    const float* pw  = (const float*)d_in[19]; const float* pb  = (const float*)d_in[20];
    float* out = (float*)d_out;

    char* p = (char*)d_ws;
    auto carve = [&](size_t bytes) { void* r = (void*)p; p += (bytes + 255) & ~(size_t)255; return r; };
    float*    e2n    = (float*)   carve((size_t)cN * 8 * 4);
    float*    dis    = (float*)   carve((size_t)cN * 4);
    ushort_t* in_src = (ushort_t*)carve((size_t)cE * 2);
    int*      in_off = (int*)     carve((size_t)cB * 513 * 4);
    float*    h      = (float*)   carve((size_t)cN * 32 * 4);
    float*    msg    = (float*)   carve((size_t)cN * cTOT * 4);
    int*      order  = (int*)     carve((size_t)cB * cK * 4);
    float*    dense  = (float*)   carve((size_t)cB * cDENSE * 4);
    float*    T2     = (float*)   carve((size_t)2000 * 32 * 4);

    const int LDS_FAT  = (512 * 36 + 512 + 516) * 4 + cEPG * 2;           // 94224
    const int LDS_THIN = (512 + 512 + 516) * 4 + cEPG * 2 + 512 * 4;      // 24592
    hipFuncSetAttribute((const void*)&gcn_layer_k<0>,
                        hipFuncAttributeMaxDynamicSharedMemorySize, LDS_FAT);
    hipFuncSetAttribute((const void*)&gcn_layer_k<1>,
                        hipFuncAttributeMaxDynamicSharedMemorySize, LDS_FAT);
    hipFuncSetAttribute((const void*)&gcn_layer_k<2>,
                        hipFuncAttributeMaxDynamicSharedMemorySize, LDS_FAT);

    tede2_kernel<<<1000, 64, 0, stream>>>(node_emb, depth_emb, W0, T2);
    prep_kernel<<<cB, 512, 0, stream>>>(edge_index, edge_attr, e2n, dis, in_src, in_off);
    gcn_layer_k<0><<<cB, 512, LDS_FAT, stream>>>(nullptr, W0, b0, dis, in_src, in_off,
                                                 h, msg, node_type, node_depth, e2n, T2, nullptr);
    gcn_layer_k<1><<<cB, 512, LDS_FAT, stream>>>(h, W1, b1, dis, in_src, in_off,
                                                 h, msg, nullptr, nullptr, nullptr, nullptr, nullptr);
    gcn_layer_k<2><<<cB, 512, LDS_FAT, stream>>>(h, W2, b2, dis, in_src, in_off,
                                                 h, msg, nullptr, nullptr, nullptr, nullptr, nullptr);
    gcn_layer_k<3><<<cB, 512, LDS_THIN, stream>>>(h, W3, b3, dis, in_src, in_off,
                                                  nullptr, msg, nullptr, nullptr, nullptr, nullptr, order);
    head_kernel<<<cB, 512, 0, stream>>>(msg, order, c1w, c1b, c2w, c2b, dense);
    pred_gemm_k<<<dim3(20, 4, 5), 256, 0, stream>>>(dense, pw, pb, out);
    (void)in_sizes; (void)n_in; (void)out_size; (void)ws_size;
}

// Round 5
// 492.357 us; speedup vs baseline: 3.7482x; 1.1337x over previous
//
#include <hip/hip_runtime.h>

typedef unsigned short ushort_t;

constexpr int cN     = 131072;
constexpr int cE     = 2097152;
constexpr int cB     = 256;
constexpr int cNPG   = 512;
constexpr int cEPG   = 8192;
constexpr int cTOT   = 97;
constexpr int cK     = 30;
constexpr int cV     = 5000;
constexpr int cDENSE = 352;

#define FMA4(A, S, W) \
    (A).x = fmaf((S), (W).x, (A).x); (A).y = fmaf((S), (W).y, (A).y); \
    (A).z = fmaf((S), (W).z, (A).z); (A).w = fmaf((S), (W).w, (A).w)

// acc += x * norm with SEPARATE mul/add roundings (match np scatter-add,
// prevent ffp-contract=fast fusing into fma)
#define MULADD4(A, X, NRM) \
    (A).x = __fadd_rn((A).x, __fmul_rn((X).x, (NRM))); \
    (A).y = __fadd_rn((A).y, __fmul_rn((X).y, (NRM))); \
    (A).z = __fadd_rn((A).z, __fmul_rn((X).z, (NRM))); \
    (A).w = __fadd_rn((A).w, __fmul_rn((X).w, (NRM)))

// ---------------------------------------------------------------------------
// prep: per-graph counting-sort into in-CSR + out-CSR, canonical (eid-sorted,
// deterministic) bucket order; e2n as two ascending-eid accumulators (ref:
// segsum(src) + segsum(masked dst)); dis; in-CSR exported for GCN layers.
// ---------------------------------------------------------------------------
__global__ __launch_bounds__(512, 1)
void prep_kernel(const int* __restrict__ ei, const float* __restrict__ attr,
                 float* __restrict__ e2n, float* __restrict__ dis,
                 ushort_t* __restrict__ in_src_g, int* __restrict__ in_off_g)
{
    __shared__ unsigned s_in[cEPG];     // (eid<<16)|src, sorted by eid per bucket
    __shared__ ushort_t s_out[cEPG];    // eid, sorted per bucket
    __shared__ int cnt[cNPG];           // packed: in<<16 | out
    __shared__ int woff[cNPG];
    const int g = blockIdx.x, tid = threadIdx.x;
    const int ebase = g * cEPG, nbase = g * cNPG;

    cnt[tid] = 0;
    __syncthreads();

    int er[16];
    #pragma unroll
    for (int j = 0; j < 16; ++j) {
        const int e  = tid + 512 * j;
        const int ls = ei[ebase + e]      - nbase;
        const int ld = ei[cE + ebase + e] - nbase;
        er[j] = ls | (ld << 16);
        atomicAdd(&cnt[ld], 65536);
        atomicAdd(&cnt[ls], 1);
    }
    __syncthreads();

    const int mycnt = cnt[tid];
    int run = mycnt;                       // inclusive scan (packed, in place)
    for (int d = 1; d < 512; d <<= 1) {
        const int add = (tid >= d) ? cnt[tid - d] : 0;
        __syncthreads();
        run += add;
        cnt[tid] = run;
        __syncthreads();
    }
    const int myexcl = run - mycnt;
    woff[tid] = myexcl;
    __syncthreads();

    #pragma unroll
    for (int j = 0; j < 16; ++j) {
        const int e  = tid + 512 * j;
        const int ls = er[j] & 0xffff;
        const int ld = er[j] >> 16;
        const int o1 = atomicAdd(&woff[ld], 65536);
        s_in[o1 >> 16] = ((unsigned)e << 16) | (unsigned)ls;
        const int o2 = atomicAdd(&woff[ls], 1);
        s_out[o2 & 0xffff] = (ushort_t)e;
    }
    __syncthreads();

    const int beg_in  = myexcl >> 16,     deg_in  = mycnt >> 16;
    const int beg_out = myexcl & 0xffff,  deg_out = mycnt & 0xffff;

    // canonical order: insertion-sort my buckets by eid (determinism)
    for (int j = beg_in + 1; j < beg_in + deg_in; ++j) {
        const unsigned x = s_in[j];
        int k = j - 1;
        while (k >= beg_in && s_in[k] > x) { s_in[k + 1] = s_in[k]; --k; }
        s_in[k + 1] = x;
    }
    for (int j = beg_out + 1; j < beg_out + deg_out; ++j) {
        const ushort_t x = s_out[j];
        int k = j - 1;
        while (k >= beg_out && s_out[k] > x) { s_out[k + 1] = s_out[k]; --k; }
        s_out[k + 1] = x;
    }
    __syncthreads();   // all buckets sorted before CSR export reads them

    // e2n: S1 = sum attr over out-edges (eid asc); S2 = sum over in-edges with
    // src != self (eid asc); e2n = S1 + S2   (matches ref's two segment_sums)
    float s1[8] = {0,0,0,0,0,0,0,0}, s2[8] = {0,0,0,0,0,0,0,0};
    for (int j = 0; j < deg_out; ++j) {
        const int eid = s_out[beg_out + j];
        const float4* ap = (const float4*)(attr + (size_t)(ebase + eid) * 8);
        const float4 x0 = ap[0], x1 = ap[1];
        s1[0] = __fadd_rn(s1[0], x0.x); s1[1] = __fadd_rn(s1[1], x0.y);
        s1[2] = __fadd_rn(s1[2], x0.z); s1[3] = __fadd_rn(s1[3], x0.w);
        s1[4] = __fadd_rn(s1[4], x1.x); s1[5] = __fadd_rn(s1[5], x1.y);
        s1[6] = __fadd_rn(s1[6], x1.z); s1[7] = __fadd_rn(s1[7], x1.w);
    }
    for (int j = 0; j < deg_in; ++j) {
        const unsigned v = s_in[beg_in + j];
        if ((int)(v & 0xffffu) != tid) {
            const int eid = (int)(v >> 16);
            const float4* ap = (const float4*)(attr + (size_t)(ebase + eid) * 8);
            const float4 x0 = ap[0], x1 = ap[1];
            s2[0] = __fadd_rn(s2[0], x0.x); s2[1] = __fadd_rn(s2[1], x0.y);
            s2[2] = __fadd_rn(s2[2], x0.z); s2[3] = __fadd_rn(s2[3], x0.w);
            s2[4] = __fadd_rn(s2[4], x1.x); s2[5] = __fadd_rn(s2[5], x1.y);
            s2[6] = __fadd_rn(s2[6], x1.z); s2[7] = __fadd_rn(s2[7], x1.w);
        }
    }
    float* eo = e2n + (size_t)(nbase + tid) * 8;
    #pragma unroll
    for (int c = 0; c < 8; ++c) eo[c] = __fadd_rn(s1[c], s2[c]);
    dis[nbase + tid] = 1.0f / sqrtf(1.0f + (float)deg_in);

    // export in-CSR (eid-sorted src lists), packed 2 per uint
    {
        unsigned* dst = (unsigned*)(in_src_g + (size_t)g * cEPG);
        for (int i = tid; i < cEPG / 2; i += 512)
            dst[i] = (s_in[2 * i] & 0xffffu) | ((s_in[2 * i + 1] & 0xffffu) << 16);
        in_off_g[g * 513 + tid] = beg_in;
        if (tid == 511) in_off_g[g * 513 + 512] = cEPG;
    }
}

// ---------------------------------------------------------------------------
// T2[(ty*20+dp)*32+c] = sum_k (ne[ty][k]+de[dp][k]) * W0[k][c], k ascending —
// exactly ref's x = ne[ty]+de[dp] (rounded add) then sequential-k fma dot.
// ---------------------------------------------------------------------------
__global__ __launch_bounds__(64, 1)
void tede2_kernel(const float* __restrict__ ne, const float* __restrict__ de,
                  const float* __restrict__ W0, float* __restrict__ T2)
{
    const int combo = blockIdx.x * 2 + (threadIdx.x >> 5);   // 0..1999
    const int c = threadIdx.x & 31;
    const int ty = combo / 20, dp = combo - ty * 20;
    const float* np_ = ne + (size_t)ty * 256;
    const float* dd_ = de + (size_t)dp * 256;
    float a = 0.f;
    for (int k = 0; k < 256; ++k)
        a = fmaf(__fadd_rn(np_[k], dd_[k]), W0[k * 32 + c], a);
    T2[(size_t)combo * 32 + c] = a;
}

// ---------------------------------------------------------------------------
// GCN layer, ref-order arithmetic:
//   hw[n] = h[n] @ W           (sequential-k fma, matches BLAS microkernel)
//   out[d] = sum_{in-edges, eid asc} hw[s]*(dis[s]*dis[d])   (mul+add, no fma)
//          + hw[d]*(dis[d]*dis[d])                           (self-loop LAST)
//          + bias; tanh (correctly rounded via double)
// LAYER 3 also does the sort-pool ranking.
// ---------------------------------------------------------------------------
template<int LAYER>
__global__ __launch_bounds__(512, 1)
void gcn_layer_k(const float* __restrict__ hprev, const float* __restrict__ Wg,
                 const float* __restrict__ bias, const float* __restrict__ dis,
                 const ushort_t* __restrict__ in_src, const int* __restrict__ in_off,
                 float* __restrict__ hout, float* __restrict__ msg,
                 const int* __restrict__ ntype, const int* __restrict__ ndepth,
                 const float* __restrict__ e2n, const float* __restrict__ T2,
                 int* __restrict__ order)
{
    constexpr bool THIN = (LAYER == 3);
    constexpr int USTR = THIN ? 1 : 36;            // bank-spreading stride
    extern __shared__ float smem[];
    float* u    = smem;                            // [512*USTR]
    float* disl = smem + 512 * USTR;               // [512]
    int* offl   = (int*)(disl + 512);              // [513->516]
    ushort_t* srcl = (ushort_t*)(offl + 516);      // [8192]
    float* key  = (float*)(srcl + cEPG);           // layer3 only [512]
    const int g = blockIdx.x, tid = threadIdx.x;
    const int n = g * cNPG + tid;

    {   // stage CSR + dis
        const uint4* s4 = (const uint4*)(in_src + (size_t)g * cEPG);
        uint4* d4 = (uint4*)srcl;
        for (int i = tid; i < cEPG / 8; i += 512) d4[i] = s4[i];
        offl[tid] = in_off[g * 513 + tid];
        if (tid == 0) offl[512] = cEPG;
    }
    const float dvd = dis[n];
    disl[tid] = dvd;

    if (!THIN) {
        float hw[32];
        if (LAYER == 0) {
            const int ty = ntype[n], dp = ndepth[n];
            float er[8];
            {
                const float4* ep = (const float4*)(e2n + (size_t)n * 8);
                const float4 x0 = ep[0], x1 = ep[1];
                er[0]=x0.x; er[1]=x0.y; er[2]=x0.z; er[3]=x0.w;
                er[4]=x1.x; er[5]=x1.y; er[6]=x1.z; er[7]=x1.w;
            }
            const float4* tp = (const float4*)(T2 + (size_t)(ty * 20 + dp) * 32);
            #pragma unroll
            for (int cq = 0; cq < 8; ++cq) {
                float4 a = tp[cq];              // k=0..255 already accumulated
                #pragma unroll
                for (int f = 0; f < 8; ++f) {   // continue chain k=256..263
                    const float4 wv = *(const float4*)(Wg + (256 + f) * 32 + cq * 4);
                    FMA4(a, er[f], wv);
                }
                hw[cq*4+0]=a.x; hw[cq*4+1]=a.y; hw[cq*4+2]=a.z; hw[cq*4+3]=a.w;
            }
        } else {
            float hr[32];
            const float4* hp = (const float4*)(hprev + (size_t)n * 32);
            #pragma unroll
            for (int q = 0; q < 8; ++q) {
                const float4 x = hp[q];
                hr[q*4+0]=x.x; hr[q*4+1]=x.y; hr[q*4+2]=x.z; hr[q*4+3]=x.w;
            }
            #pragma unroll
            for (int cq = 0; cq < 8; ++cq) {
                float4 a = {0.f, 0.f, 0.f, 0.f};
                #pragma unroll
                for (int k = 0; k < 32; ++k) {  // uniform address -> s_load
                    const float4 wv = *(const float4*)(Wg + k * 32 + cq * 4);
                    FMA4(a, hr[k], wv);
                }
                hw[cq*4+0]=a.x; hw[cq*4+1]=a.y; hw[cq*4+2]=a.z; hw[cq*4+3]=a.w;
            }
        }
        {
            float4* up = (float4*)(u + tid * 36);
            #pragma unroll
            for (int cq = 0; cq < 8; ++cq) {
                float4 o; o.x=hw[cq*4+0]; o.y=hw[cq*4+1];
                o.z=hw[cq*4+2]; o.w=hw[cq*4+3];
                up[cq] = o;
            }
        }
        __syncthreads();

        // edge gather (eid ascending), per-term (dis[s]*dis[d]) mul then add
        float4 acc[8];
        #pragma unroll
        for (int cq = 0; cq < 8; ++cq) acc[cq] = {0.f, 0.f, 0.f, 0.f};
        const int beg = offl[tid], dnum = offl[tid + 1] - beg;
        for (int j = 0; j < dnum; ++j) {
            const int s = srcl[beg + j];
            const float norm = __fmul_rn(disl[s], dvd);
            const float4* up = (const float4*)(u + s * 36);
            #pragma unroll
            for (int cq = 0; cq < 8; ++cq) {
                const float4 x = up[cq];
                MULADD4(acc[cq], x, norm);
            }
        }
        // self-loop LAST (ref: appended after all edges)
        {
            const float normS = __fmul_rn(dvd, dvd);
            const float4* up = (const float4*)(u + tid * 36);
            #pragma unroll
            for (int cq = 0; cq < 8; ++cq) {
                const float4 x = up[cq];
                MULADD4(acc[cq], x, normS);
            }
        }

        // + bias, tanh (correctly rounded)
        float outv[32];
        #pragma unroll
        for (int cq = 0; cq < 8; ++cq) {
            const float4 bv = *(const float4*)(bias + cq * 4);  // s_load
            outv[cq*4+0] = (float)tanh((double)__fadd_rn(acc[cq].x, bv.x));
            outv[cq*4+1] = (float)tanh((double)__fadd_rn(acc[cq].y, bv.y));
            outv[cq*4+2] = (float)tanh((double)__fadd_rn(acc[cq].z, bv.z));
            outv[cq*4+3] = (float)tanh((double)__fadd_rn(acc[cq].w, bv.w));
        }
        float4* ho = (float4*)(hout + (size_t)n * 32);
        #pragma unroll
        for (int cq = 0; cq < 8; ++cq) {
            float4 o; o.x = outv[cq*4+0]; o.y = outv[cq*4+1];
            o.z = outv[cq*4+2]; o.w = outv[cq*4+3];
            ho[cq] = o;
        }
        float* mrow = msg + (size_t)n * cTOT + LAYER * 32;
        #pragma unroll
        for (int c = 0; c < 32; ++c) mrow[c] = outv[c];
    } else {
        float hr[32];
        const float4* hp = (const float4*)(hprev + (size_t)n * 32);
        #pragma unroll
        for (int q = 0; q < 8; ++q) {
            const float4 x = hp[q];
            hr[q*4+0]=x.x; hr[q*4+1]=x.y; hr[q*4+2]=x.z; hr[q*4+3]=x.w;
        }
        float s_ = 0.f;
        #pragma unroll
        for (int k = 0; k < 32; ++k) s_ = fmaf(hr[k], Wg[k], s_);  // s_load
        u[tid] = s_;
        __syncthreads();
        const int beg = offl[tid], dnum = offl[tid + 1] - beg;
        float gs = 0.f;
        for (int j = 0; j < dnum; ++j) {
            const int s = srcl[beg + j];
            gs = __fadd_rn(gs, __fmul_rn(u[s], __fmul_rn(disl[s], dvd)));
        }
        gs = __fadd_rn(gs, __fmul_rn(u[tid], __fmul_rn(dvd, dvd)));  // self last
        const float o = (float)tanh((double)__fadd_rn(gs, bias[0]));
        msg[(size_t)n * cTOT + 96] = o;
        key[tid] = o;
        __syncthreads();
        // sort-pool rank (stable: desc key, asc index)
        int rank = 0;
        for (int jj = 0; jj < 128; ++jj) {
            const float4 kq = *(const float4*)(key + jj * 4);
            rank += (kq.x > o) || (kq.x == o && (jj*4+0) < tid);
            rank += (kq.y > o) || (kq.y == o && (jj*4+1) < tid);
            rank += (kq.z > o) || (kq.z == o && (jj*4+2) < tid);
            rank += (kq.w > o) || (kq.w == o && (jj*4+3) < tid);
        }
        if (rank < cK) order[g * cK + rank] = n;
    }
}

// ---------------------------------------------------------------------------
// head: gather pooled rows + conv1 + relu + maxpool + conv2 + relu -> dense
// ---------------------------------------------------------------------------
__global__ __launch_bounds__(512, 1)
void head_kernel(const float* __restrict__ msg, const int* __restrict__ order,
                 const float* __restrict__ c1w, const float* __restrict__ c1b,
                 const float* __restrict__ c2w, const float* __restrict__ c2b,
                 float* __restrict__ dense)
{
    __shared__ float P[cK * cTOT];
    __shared__ float w1[16 * cTOT];
    __shared__ float w2[32 * 16 * 5];
    __shared__ float bb[48];
    __shared__ float Cb[16 * 30];
    __shared__ float Mb[16 * 15];
    const int g = blockIdx.x, tid = threadIdx.x;
    for (int i = tid; i < cK * cTOT; i += 512) {
        const int r = i / cTOT, ii = i - r * cTOT;
        P[i] = msg[(size_t)order[g * cK + r] * cTOT + ii];
    }
    for (int i = tid; i < 16 * cTOT; i += 512) w1[i] = c1w[i];
    for (int i = tid; i < 2560; i += 512) w2[i] = c2w[i];
    if (tid < 16) bb[tid] = c1b[tid];
    else if (tid < 48) bb[tid] = c2b[tid - 16];
    __syncthreads();
    if (tid < 480) {
        const int o = tid / 30, k = tid - o * 30;
        float s = bb[o];
        for (int i = 0; i < cTOT; ++i) s = fmaf(P[k * cTOT + i], w1[o * cTOT + i], s);
        Cb[tid] = fmaxf(s, 0.f);
    }
    __syncthreads();
    if (tid < 240) {
        const int o = tid / 15, p = tid - o * 15;
        Mb[tid] = fmaxf(Cb[o * 30 + 2 * p], Cb[o * 30 + 2 * p + 1]);
    }
    __syncthreads();
    if (tid < cDENSE) {
        const int o2 = tid / 11, q = tid - o2 * 11;
        float s = bb[16 + o2];
        #pragma unroll
        for (int i = 0; i < 16; ++i)
            #pragma unroll
            for (int w = 0; w < 5; ++w)
                s = fmaf(Mb[i * 15 + q + w], w2[(o2 * 16 + i) * 5 + w], s);
        dense[(size_t)g * cDENSE + tid] = fmaxf(s, 0.f);
    }
}

// ---------------------------------------------------------------------------
// pred GEMM v2: per s-slice C[256,5000] = D[256,352] @ W[352,5000] + b.
// LDS-tiled: BM=64, BN=128, BK=32, 256 threads, 4m x 8n register tile.
// Accumulation ascending-k sequential per output (deterministic, ref-like).
// ---------------------------------------------------------------------------
__global__ __launch_bounds__(256, 4)
void pred_gemm_k(const float* __restrict__ dense, const float* __restrict__ pw,
                 const float* __restrict__ pb, float* __restrict__ out)
{
    __shared__ float As[32][68];     // [k][m], +4 pad
    __shared__ float Bs[32][128];    // [k][v]
    const int s  = blockIdx.z;
    const int b0 = blockIdx.y * 64;
    const int vn = blockIdx.x * 128;
    const int tid = threadIdx.x;
    const int tm = tid >> 4, tn = tid & 15;       // 16 x 16 thread grid
    const float* wbase = pw + (size_t)s * cDENSE * cV;

    // staging index maps
    const int ar = tid >> 2;            // A: row 0..63
    const int ak = (tid & 3) * 8;       // A: k offset {0,8,16,24}
    const int bk = tid >> 3;            // B: k row 0..31
    const int bv = (tid & 7) * 16;      // B: v offset {0..112}

    float4 acc[4][2];
    #pragma unroll
    for (int mi = 0; mi < 4; ++mi) {
        acc[mi][0] = {0.f, 0.f, 0.f, 0.f};
        acc[mi][1] = {0.f, 0.f, 0.f, 0.f};
    }

    for (int ks = 0; ks < cDENSE; ks += 32) {
        // fetch tiles to registers
        const float* arow = dense + (size_t)(b0 + ar) * cDENSE + ks + ak;
        const float4 a0 = *(const float4*)(arow);
        const float4 a1 = *(const float4*)(arow + 4);
        float4 bq[4];
        {
            const int gv = vn + bv;
            const float* brow = wbase + (size_t)(ks + bk) * cV + gv;
            if (gv + 16 <= cV) {
                #pragma unroll
                for (int q = 0; q < 4; ++q) bq[q] = *(const float4*)(brow + q * 4);
            } else {
                #pragma unroll
                for (int q = 0; q < 4; ++q) {
                    #pragma unroll
                    for (int j = 0; j < 4; ++j) {
                        const int vv = gv + q * 4 + j;
                        ((float*)&bq[q])[j] = (vv < cV) ? brow[q * 4 + j] : 0.f;
                    }
                }
            }
        }
        __syncthreads();   // previous iteration's LDS reads complete
        // store A transposed: As[k][m]
        As[ak + 0][ar] = a0.x; As[ak + 1][ar] = a0.y;
        As[ak + 2][ar] = a0.z; As[ak + 3][ar] = a0.w;
        As[ak + 4][ar] = a1.x; As[ak + 5][ar] = a1.y;
        As[ak + 6][ar] = a1.z; As[ak + 7][ar] = a1.w;
        // store B: Bs[k][v]
        #pragma unroll
        for (int q = 0; q < 4; ++q)
            *(float4*)(&Bs[bk][bv + q * 4]) = bq[q];
        __syncthreads();
        // inner product, kk ascending
        #pragma unroll
        for (int kk = 0; kk < 32; ++kk) {
            const float4 av  = *(const float4*)(&As[kk][tm * 4]);
            const float4 bv0 = *(const float4*)(&Bs[kk][tn * 8]);
            const float4 bv1 = *(const float4*)(&Bs[kk][tn * 8 + 4]);
            FMA4(acc[0][0], av.x, bv0); FMA4(acc[0][1], av.x, bv1);
            FMA4(acc[1][0], av.y, bv0); FMA4(acc[1][1], av.y, bv1);
            FMA4(acc[2][0], av.z, bv0); FMA4(acc[2][1], av.z, bv1);
            FMA4(acc[3][0], av.w, bv0); FMA4(acc[3][1], av.w, bv1);
        }
    }

    // epilogue: + bias, store (v guard: gv0 multiple of 8, tiles never straddle)
    const int gv0 = vn + tn * 8;
    if (gv0 < cV) {
        const float4 pb0 = *(const float4*)(pb + (size_t)s * cV + gv0);
        const float4 pb1 = *(const float4*)(pb + (size_t)s * cV + gv0 + 4);
        #pragma unroll
        for (int mi = 0; mi < 4; ++mi) {
            const int row = b0 + tm * 4 + mi;
            float* op = out + ((size_t)s * cB + row) * cV + gv0;
            float4 o0, o1;
            o0.x = acc[mi][0].x + pb0.x; o0.y = acc[mi][0].y + pb0.y;
            o0.z = acc[mi][0].z + pb0.z; o0.w = acc[mi][0].w + pb0.w;
            o1.x = acc[mi][1].x + pb1.x; o1.y = acc[mi][1].y + pb1.y;
            o1.z = acc[mi][1].z + pb1.z; o1.w = acc[mi][1].w + pb1.w;
            *(float4*)(op)     = o0;
            *(float4*)(op + 4) = o1;
        }
    }
}

// ---------------------------------------------------------------------------
extern "C" void kernel_launch(void* const* d_in, const int* in_sizes, int n_in,
                              void* d_out, int out_size, void* d_ws, size_t ws_size,
                              hipStream_t stream)
{
    const int*   node_type  = (const int*)  d_in[0];
    const int*   node_depth = (const int*)  d_in[1];
    const int*   edge_index = (const int*)  d_in[2];
    const float* edge_attr  = (const float*)d_in[3];
    const float* node_emb   = (const float*)d_in[5];
    const float* depth_emb  = (const float*)d_in[6];
    const float* W0 = (const float*)d_in[7];  const float* b0 = (const float*)d_in[8];
    const float* W1 = (const float*)d_in[9];  const float* b1 = (const float*)d_in[10];
    const float* W2 = (const float*)d_in[11]; const float* b2 = (const float*)d_in[12];
    const float* W3 = (const float*)d_in[13]; const float* b3 = (const float*)d_in[14];
    const float* c1w = (const float*)d_in[15]; const float* c1b = (const float*)d_in[16];
    const float* c2w = (const float*)d_in[17]; const float* c2b = (const float*)d_in[18];
    const float* pw  = (const float*)d_in[19]; const float* pb  = (const float*)d_in[20];
    float* out = (float*)d_out;

    char* p = (char*)d_ws;
    auto carve = [&](size_t bytes) { void* r = (void*)p; p += (bytes + 255) & ~(size_t)255; return r; };
    float*    e2n    = (float*)   carve((size_t)cN * 8 * 4);
    float*    dis    = (float*)   carve((size_t)cN * 4);
    ushort_t* in_src = (ushort_t*)carve((size_t)cE * 2);
    int*      in_off = (int*)     carve((size_t)cB * 513 * 4);
    float*    h      = (float*)   carve((size_t)cN * 32 * 4);
    float*    msg    = (float*)   carve((size_t)cN * cTOT * 4);
    int*      order  = (int*)     carve((size_t)cB * cK * 4);
    float*    dense  = (float*)   carve((size_t)cB * cDENSE * 4);
    float*    T2     = (float*)   carve((size_t)2000 * 32 * 4);

    const int LDS_FAT  = (512 * 36 + 512 + 516) * 4 + cEPG * 2;           // 94224
    const int LDS_THIN = (512 + 512 + 516) * 4 + cEPG * 2 + 512 * 4;      // 24592
    hipFuncSetAttribute((const void*)&gcn_layer_k<0>,
                        hipFuncAttributeMaxDynamicSharedMemorySize, LDS_FAT);
    hipFuncSetAttribute((const void*)&gcn_layer_k<1>,
                        hipFuncAttributeMaxDynamicSharedMemorySize, LDS_FAT);
    hipFuncSetAttribute((const void*)&gcn_layer_k<2>,
                        hipFuncAttributeMaxDynamicSharedMemorySize, LDS_FAT);

    tede2_kernel<<<1000, 64, 0, stream>>>(node_emb, depth_emb, W0, T2);
    prep_kernel<<<cB, 512, 0, stream>>>(edge_index, edge_attr, e2n, dis, in_src, in_off);
    gcn_layer_k<0><<<cB, 512, LDS_FAT, stream>>>(nullptr, W0, b0, dis, in_src, in_off,
                                                 h, msg, node_type, node_depth, e2n, T2, nullptr);
    gcn_layer_k<1><<<cB, 512, LDS_FAT, stream>>>(h, W1, b1, dis, in_src, in_off,
                                                 h, msg, nullptr, nullptr, nullptr, nullptr, nullptr);
    gcn_layer_k<2><<<cB, 512, LDS_FAT, stream>>>(h, W2, b2, dis, in_src, in_off,
                                                 h, msg, nullptr, nullptr, nullptr, nullptr, nullptr);
    gcn_layer_k<3><<<cB, 512, LDS_THIN, stream>>>(h, W3, b3, dis, in_src, in_off,
                                                  nullptr, msg, nullptr, nullptr, nullptr, nullptr, order);
    head_kernel<<<cB, 512, 0, stream>>>(msg, order, c1w, c1b, c2w, c2b, dense);
    pred_gemm_k<<<dim3(40, 4, 5), 256, 0, stream>>>(dense, pw, pb, out);
    (void)in_sizes; (void)n_in; (void)out_size; (void)ws_size;
}